// Round 2
// baseline (180.151 us; speedup 1.0000x reference)
//
#include <hip/hip_runtime.h>

// CPRPackedLinear: out(64x11008) = xperm[:, :1024] @ deq6(W_high) + xperm[:, 1024:] @ deq5(W_low) + bias
//
// R2: Round 1 doubled occupancy (23->42%) with ZERO speedup -> not wave-starved.
// Root cause: __syncthreads() drains vmcnt(0), killing the cross-iteration register
// prefetch (every iteration pays full HBM/L3 latency serially).
// Fix: raw s_barrier with lgkmcnt-only wait (prefetch loads stay in flight across
// the barrier, 8-phase/T3+T4 pattern) + depth-2 register prefetch (packed ints,
// scale, and A-fragment for tile t+2 issued at tile t) with explicit even/odd
// register slots (static indexing only).

#define NFEAT 11008
#define KTOT  4096

typedef _Float16 half8 __attribute__((ext_vector_type(8)));
typedef float    f32x4 __attribute__((ext_vector_type(4)));

// barrier that does NOT drain vmcnt: waits only LDS ops (my ds_write), keeps
// register-destination global loads in flight across the barrier.
#define BARRIER_KEEP_INFLIGHT()                                   \
    do {                                                          \
        asm volatile("s_waitcnt lgkmcnt(0)" ::: "memory");        \
        __builtin_amdgcn_s_barrier();                             \
        asm volatile("" ::: "memory");                            \
    } while (0)

// ---------------- prep: x_perm -> fp16 in MFMA A-fragment layout ----------------
// xfrag flat idx = ((s*4 + mt)*64 + lane)*8 + j
//   holds x[m = mt*16 + (lane&15)][ col_indices[k = s*32 + (lane>>4)*8 + j] ]
__global__ __launch_bounds__(256) void prep_xfrag(const float* __restrict__ x,
                                                  const int* __restrict__ col,
                                                  _Float16* __restrict__ xfrag) {
    int idx = blockIdx.x * 256 + threadIdx.x;          // 0..262143
    int j  = idx & 7;
    int l  = (idx >> 3) & 63;
    int mt = (idx >> 9) & 3;
    int s  = idx >> 11;
    int k  = s * 32 + ((l >> 4) << 3) + j;
    int m  = mt * 16 + (l & 15);
    xfrag[idx] = (_Float16)x[m * KTOT + col[k]];
}

// ---------------- main GEMM ----------------
// grid.x = 172 (64-col tiles), grid.y = 4 (K chunks of 1024: chunk0=6bit high, 1..3=5bit low)
// block = 512 threads = 8 waves: wave w -> (mt = w&3, qm = w>>2); dequant kg = wave
__global__ __launch_bounds__(512) void gemm_kernel(const int* __restrict__ Wh,
                                                   const int* __restrict__ Wl,
                                                   const float* __restrict__ sh,
                                                   const float* __restrict__ sl,
                                                   const _Float16* __restrict__ xfrag,
                                                   float* __restrict__ dst,
                                                   int atomic_mode) {
    const int n0   = blockIdx.x * 64;
    const int kc   = blockIdx.y;
    const int tid  = threadIdx.x;
    const int lane = tid & 63;
    const int wave = tid >> 6;                          // 0..7

    // B fragments in LDS, fragment-ready, double-buffered (buf0=even tile, buf1=odd):
    // frag (nt, q), lane L at half-offset (((nt*2+q)*64 + L) + nt)*8
    __shared__ _Float16 Wfrag[2][8 * 64 * 8 + 4 * 8];

    f32x4 acc[4];
#pragma unroll
    for (int i = 0; i < 4; ++i) acc[i] = (f32x4){0.f, 0.f, 0.f, 0.f};

    // ---- dequant role: thread owns (col = lane, k-group kg = wave) ----
    const int col  = lane;
    const int nt   = col >> 4;
    const int n_in = col & 15;
    const int kg   = wave;                              // 0..7, 8 k-rows each
    const int q_w  = kg >> 2, quad = kg & 3;
    const int woff = (((nt * 2 + q_w) * 64 + quad * 16 + n_in) + nt) * 8;

    // ---- MFMA role ----
    const int mt = wave & 3;                            // m-tile (16 rows)
    const int qm = wave >> 2;                           // which k-half-step of the tile

    auto aoff = [&](int t) {
        return (((kc * 32 + t * 2 + qm) * 4 + mt) * 64 + lane) << 3;
    };
    auto mfma4 = [&](const _Float16* wf, half8 a) {
#pragma unroll
        for (int j = 0; j < 4; ++j) {
            half8 b = *(const half8*)&wf[(((j * 2 + qm) * 64 + lane) + j) * 8];
            acc[j] = __builtin_amdgcn_mfma_f32_16x16x32_f16(a, b, acc[j], 0, 0, 0);
        }
    };

    if (kc == 0) {
        // ================= 6-bit region =================
        auto deq6 = [](int b0, int b1, int b2, int b3, int b4, int b5, float s) -> half8 {
            int v0 = b0 & 63;
            int v1 = ((b0 >> 6) & 3) | ((b1 & 15) << 2);
            int v2 = ((b1 >> 4) & 15) | ((b2 & 3) << 4);
            int v3 = (b2 >> 2) & 63;
            int v4 = b3 & 63;
            int v5 = ((b3 >> 6) & 3) | ((b4 & 15) << 2);
            int v6 = ((b4 >> 4) & 15) | ((b5 & 3) << 4);
            int v7 = (b5 >> 2) & 63;
            half8 w;
            w[0] = (_Float16)(((float)v0 - 31.0f) * s);
            w[1] = (_Float16)(((float)v1 - 31.0f) * s);
            w[2] = (_Float16)(((float)v2 - 31.0f) * s);
            w[3] = (_Float16)(((float)v3 - 31.0f) * s);
            w[4] = (_Float16)(((float)v4 - 31.0f) * s);
            w[5] = (_Float16)(((float)v5 - 31.0f) * s);
            w[6] = (_Float16)(((float)v6 - 31.0f) * s);
            w[7] = (_Float16)(((float)v7 - 31.0f) * s);
            return w;
        };
        const int*   base  = Wh + n0 + col;
        const float* sbase = sh + n0 + col;
        int A0, A1, A2, A3, A4, A5; float As;           // even-tile slot
        int B0, B1, B2, B3, B4, B5; float Bs;           // odd-tile slot
        half8 xaE, xaO;
        {   // prologue: tiles 0 and 1
            const int* bp = base + 3 * (kg * 2) * NFEAT;
            A0 = bp[0];         A1 = bp[NFEAT];     A2 = bp[2 * NFEAT];
            A3 = bp[3 * NFEAT]; A4 = bp[4 * NFEAT]; A5 = bp[5 * NFEAT];
            As = sbase[0];
            bp = base + 3 * (16 + kg * 2) * NFEAT;
            B0 = bp[0];         B1 = bp[NFEAT];     B2 = bp[2 * NFEAT];
            B3 = bp[3 * NFEAT]; B4 = bp[4 * NFEAT]; B5 = bp[5 * NFEAT];
            Bs = sbase[0];
            xaE = *(const half8*)(xfrag + aoff(0));
            xaO = *(const half8*)(xfrag + aoff(1));
        }
        for (int i = 0; i < 8; ++i) {
            {   // ---- even phase: tile 2i ----
                half8 w = deq6(A0, A1, A2, A3, A4, A5, As);
                half8 acur = xaE;
                *(half8*)&Wfrag[0][woff] = w;
                const int tp = (i < 7) ? 2 * i + 2 : 14;    // prefetch depth 2
                const int* bp = base + 3 * (tp * 16 + kg * 2) * NFEAT;
                A0 = bp[0];         A1 = bp[NFEAT];     A2 = bp[2 * NFEAT];
                A3 = bp[3 * NFEAT]; A4 = bp[4 * NFEAT]; A5 = bp[5 * NFEAT];
                As = sbase[(tp >> 1) * NFEAT];
                xaE = *(const half8*)(xfrag + aoff(tp));
                BARRIER_KEEP_INFLIGHT();
                mfma4(Wfrag[0], acur);
            }
            {   // ---- odd phase: tile 2i+1 ----
                half8 w = deq6(B0, B1, B2, B3, B4, B5, Bs);
                half8 acur = xaO;
                *(half8*)&Wfrag[1][woff] = w;
                const int tp = (i < 7) ? 2 * i + 3 : 15;
                const int* bp = base + 3 * (tp * 16 + kg * 2) * NFEAT;
                B0 = bp[0];         B1 = bp[NFEAT];     B2 = bp[2 * NFEAT];
                B3 = bp[3 * NFEAT]; B4 = bp[4 * NFEAT]; B5 = bp[5 * NFEAT];
                Bs = sbase[(tp >> 1) * NFEAT];
                xaO = *(const half8*)(xfrag + aoff(tp));
                BARRIER_KEEP_INFLIGHT();
                mfma4(Wfrag[1], acur);
            }
        }
    } else {
        // ================= 5-bit region =================
        auto deq5 = [](int b0, int b1, int b2, int b3, int b4, float s) -> half8 {
            int v0 = b0 & 31;
            int v1 = ((b0 >> 5) & 7) | ((b1 & 3) << 3);
            int v2 = (b1 >> 2) & 31;
            int v3 = ((b1 >> 7) & 1) | ((b2 & 15) << 1);
            int v4 = ((b2 >> 4) & 15) | ((b3 & 1) << 4);
            int v5 = (b3 >> 1) & 31;
            int v6 = ((b3 >> 6) & 3) | ((b4 & 7) << 2);
            int v7 = (b4 >> 3) & 31;
            half8 w;
            w[0] = (_Float16)(((float)v0 - 15.0f) * s);
            w[1] = (_Float16)(((float)v1 - 15.0f) * s);
            w[2] = (_Float16)(((float)v2 - 15.0f) * s);
            w[3] = (_Float16)(((float)v3 - 15.0f) * s);
            w[4] = (_Float16)(((float)v4 - 15.0f) * s);
            w[5] = (_Float16)(((float)v5 - 15.0f) * s);
            w[6] = (_Float16)(((float)v6 - 15.0f) * s);
            w[7] = (_Float16)(((float)v7 - 15.0f) * s);
            return w;
        };
        const int*   base  = Wl + n0 + col;
        const float* sbase = sl + n0 + col;
        const int Gbase     = (kc - 1) * 128;           // G = Gbase + t*8 + kg
        const int sbase_row = (kc - 1) * 8;             // scale row = sbase_row + (t>>1)
        int A0, A1, A2, A3, A4; float As;
        int B0, B1, B2, B3, B4; float Bs;
        half8 xaE, xaO;
        {   // prologue: tiles 0 and 1
            const int* bp = base + 5 * (Gbase + kg) * NFEAT;
            A0 = bp[0]; A1 = bp[NFEAT]; A2 = bp[2 * NFEAT];
            A3 = bp[3 * NFEAT]; A4 = bp[4 * NFEAT];
            As = sbase[sbase_row * NFEAT];
            bp = base + 5 * (Gbase + 8 + kg) * NFEAT;
            B0 = bp[0]; B1 = bp[NFEAT]; B2 = bp[2 * NFEAT];
            B3 = bp[3 * NFEAT]; B4 = bp[4 * NFEAT];
            Bs = sbase[sbase_row * NFEAT];
            xaE = *(const half8*)(xfrag + aoff(0));
            xaO = *(const half8*)(xfrag + aoff(1));
        }
        for (int i = 0; i < 8; ++i) {
            {   // ---- even phase: tile 2i ----
                half8 w = deq5(A0, A1, A2, A3, A4, As);
                half8 acur = xaE;
                *(half8*)&Wfrag[0][woff] = w;
                const int tp = (i < 7) ? 2 * i + 2 : 14;
                const int* bp = base + 5 * (Gbase + tp * 8 + kg) * NFEAT;
                A0 = bp[0]; A1 = bp[NFEAT]; A2 = bp[2 * NFEAT];
                A3 = bp[3 * NFEAT]; A4 = bp[4 * NFEAT];
                As = sbase[(sbase_row + (tp >> 1)) * NFEAT];
                xaE = *(const half8*)(xfrag + aoff(tp));
                BARRIER_KEEP_INFLIGHT();
                mfma4(Wfrag[0], acur);
            }
            {   // ---- odd phase: tile 2i+1 ----
                half8 w = deq5(B0, B1, B2, B3, B4, Bs);
                half8 acur = xaO;
                *(half8*)&Wfrag[1][woff] = w;
                const int tp = (i < 7) ? 2 * i + 3 : 15;
                const int* bp = base + 5 * (Gbase + tp * 8 + kg) * NFEAT;
                B0 = bp[0]; B1 = bp[NFEAT]; B2 = bp[2 * NFEAT];
                B3 = bp[3 * NFEAT]; B4 = bp[4 * NFEAT];
                Bs = sbase[(sbase_row + (tp >> 1)) * NFEAT];
                xaO = *(const half8*)(xfrag + aoff(tp));
                BARRIER_KEEP_INFLIGHT();
                mfma4(Wfrag[1], acur);
            }
        }
    }

    // ---- epilogue: fold q=1 waves into q=0 waves via LDS, then store ----
    __syncthreads();                                    // full drain (also retires dead prefetches)
    float* red = (float*)&Wfrag[0][0];                  // 16*256 floats = 16 KB
    if (wave >= 4) {
#pragma unroll
        for (int j = 0; j < 4; ++j)
#pragma unroll
            for (int r = 0; r < 4; ++r)
                red[(j * 4 + r) * 256 + (wave - 4) * 64 + lane] = acc[j][r];
    }
    __syncthreads();
    if (wave < 4) {
#pragma unroll
        for (int j = 0; j < 4; ++j)
#pragma unroll
            for (int r = 0; r < 4; ++r)
                acc[j][r] += red[(j * 4 + r) * 256 + wave * 64 + lane];

        // D row = wave*16 + (lane>>4)*4 + r, col = lane&15
        const int rb = wave * 16 + ((lane >> 4) << 2);
        const int cb = lane & 15;
        if (atomic_mode) {
#pragma unroll
            for (int j = 0; j < 4; ++j)
#pragma unroll
                for (int r = 0; r < 4; ++r)
                    atomicAdd(&dst[(rb + r) * NFEAT + n0 + j * 16 + cb], acc[j][r]);
        } else {
            float* base = dst + (size_t)kc * 64 * NFEAT;
#pragma unroll
            for (int j = 0; j < 4; ++j)
#pragma unroll
                for (int r = 0; r < 4; ++r)
                    base[(rb + r) * NFEAT + n0 + j * 16 + cb] = acc[j][r];
        }
    }
}

// ---------------- reduce: out = bias + sum_kc partial[kc] ----------------
__global__ __launch_bounds__(256) void reduce_out(const float* __restrict__ part,
                                                  const float* __restrict__ bias,
                                                  float* __restrict__ out) {
    const int idx = blockIdx.x * 256 + threadIdx.x;    // 0..176127 (float4 units)
    const int f   = idx * 4;
    const int n   = f % NFEAT;                          // NFEAT % 4 == 0 -> same row
    f32x4 a = *(const f32x4*)(part + f);
    f32x4 b = *(const f32x4*)(part + 704512 + f);
    f32x4 c = *(const f32x4*)(part + 2 * 704512 + f);
    f32x4 d = *(const f32x4*)(part + 3 * 704512 + f);
    f32x4 bi = *(const f32x4*)(bias + n);
    *(f32x4*)(out + f) = a + b + c + d + bi;
}

__global__ __launch_bounds__(256) void init_bias(const float* __restrict__ bias,
                                                 float* __restrict__ out) {
    const int idx = blockIdx.x * 256 + threadIdx.x;    // 0..704511
    out[idx] = bias[idx % NFEAT];
}

extern "C" void kernel_launch(void* const* d_in, const int* in_sizes, int n_in,
                              void* d_out, int out_size, void* d_ws, size_t ws_size,
                              hipStream_t stream) {
    const float* x    = (const float*)d_in[0];
    const int*   Wh   = (const int*)d_in[1];
    const int*   Wl   = (const int*)d_in[2];
    const float* sh   = (const float*)d_in[3];
    const float* sl   = (const float*)d_in[4];
    const int*   col  = (const int*)d_in[5];
    const float* bias = (const float*)d_in[6];
    float* out = (float*)d_out;

    _Float16* xfrag = (_Float16*)d_ws;                 // 512 KB
    const size_t xfrag_bytes = 64 * KTOT * sizeof(_Float16);
    const size_t part_bytes  = 4ull * 64 * NFEAT * sizeof(float);   // 11.27 MB

    prep_xfrag<<<1024, 256, 0, stream>>>(x, col, xfrag);

    dim3 grid(172, 4);
    if (ws_size >= xfrag_bytes + part_bytes) {
        float* part = (float*)((char*)d_ws + xfrag_bytes);
        gemm_kernel<<<grid, 512, 0, stream>>>(Wh, Wl, sh, sl, xfrag, part, 0);
        reduce_out<<<688, 256, 0, stream>>>(part, bias, out);
    } else {
        init_bias<<<2752, 256, 0, stream>>>(bias, out);
        gemm_kernel<<<grid, 512, 0, stream>>>(Wh, Wl, sh, sl, xfrag, out, 1);
    }
}

// Round 3
// 179.519 us; speedup vs baseline: 1.0035x; 1.0035x over previous
//
#include <hip/hip_runtime.h>

// CPRPackedLinear: out(64x11008) = xperm[:, :1024] @ deq6(W_high) + xperm[:, 1024:] @ deq5(W_low) + bias
//
// R3: R2's pipeline was correct but register-starved. VGPR_Count=48 proves the
// compiler serialized the depth-2 prefetch (needs ~26 data regs in flight) to hit
// its default max-occupancy register target (8 waves/EU -> <=64 VGPR for a
// 512-thread block). Arithmetic: 1800 wave-loads/CU retiring one per 68 cy =
// ~13 loads in flight per CU = serialized latency. Fix: __launch_bounds__(512, 2)
// declares we only need 2 waves/EU -> 256-VGPR budget -> scheduler can keep the
// depth-2 pipeline (16 loads/wave) in flight. Everything else unchanged from R2.

#define NFEAT 11008
#define KTOT  4096

typedef _Float16 half8 __attribute__((ext_vector_type(8)));
typedef float    f32x4 __attribute__((ext_vector_type(4)));

// barrier that does NOT drain vmcnt: waits only LDS ops (my ds_write), keeps
// register-destination global loads in flight across the barrier.
#define BARRIER_KEEP_INFLIGHT()                                   \
    do {                                                          \
        asm volatile("s_waitcnt lgkmcnt(0)" ::: "memory");        \
        __builtin_amdgcn_s_barrier();                             \
        asm volatile("" ::: "memory");                            \
    } while (0)

// ---------------- prep: x_perm -> fp16 in MFMA A-fragment layout ----------------
// xfrag flat idx = ((s*4 + mt)*64 + lane)*8 + j
//   holds x[m = mt*16 + (lane&15)][ col_indices[k = s*32 + (lane>>4)*8 + j] ]
__global__ __launch_bounds__(256) void prep_xfrag(const float* __restrict__ x,
                                                  const int* __restrict__ col,
                                                  _Float16* __restrict__ xfrag) {
    int idx = blockIdx.x * 256 + threadIdx.x;          // 0..262143
    int j  = idx & 7;
    int l  = (idx >> 3) & 63;
    int mt = (idx >> 9) & 3;
    int s  = idx >> 11;
    int k  = s * 32 + ((l >> 4) << 3) + j;
    int m  = mt * 16 + (l & 15);
    xfrag[idx] = (_Float16)x[m * KTOT + col[k]];
}

// ---------------- main GEMM ----------------
// grid.x = 172 (64-col tiles), grid.y = 4 (K chunks of 1024: chunk0=6bit high, 1..3=5bit low)
// block = 512 threads = 8 waves: wave w -> (mt = w&3, qm = w>>2); dequant kg = wave
// __launch_bounds__(512, 2): 2 waves/EU min -> 256-VGPR budget (the whole point of R3)
__global__ __launch_bounds__(512, 2) void gemm_kernel(const int* __restrict__ Wh,
                                                      const int* __restrict__ Wl,
                                                      const float* __restrict__ sh,
                                                      const float* __restrict__ sl,
                                                      const _Float16* __restrict__ xfrag,
                                                      float* __restrict__ dst,
                                                      int atomic_mode) {
    const int n0   = blockIdx.x * 64;
    const int kc   = blockIdx.y;
    const int tid  = threadIdx.x;
    const int lane = tid & 63;
    const int wave = tid >> 6;                          // 0..7

    // B fragments in LDS, fragment-ready, double-buffered (buf0=even tile, buf1=odd):
    // frag (nt, q), lane L at half-offset (((nt*2+q)*64 + L) + nt)*8
    __shared__ _Float16 Wfrag[2][8 * 64 * 8 + 4 * 8];

    f32x4 acc[4];
#pragma unroll
    for (int i = 0; i < 4; ++i) acc[i] = (f32x4){0.f, 0.f, 0.f, 0.f};

    // ---- dequant role: thread owns (col = lane, k-group kg = wave) ----
    const int col  = lane;
    const int nt   = col >> 4;
    const int n_in = col & 15;
    const int kg   = wave;                              // 0..7, 8 k-rows each
    const int q_w  = kg >> 2, quad = kg & 3;
    const int woff = (((nt * 2 + q_w) * 64 + quad * 16 + n_in) + nt) * 8;

    // ---- MFMA role ----
    const int mt = wave & 3;                            // m-tile (16 rows)
    const int qm = wave >> 2;                           // which k-half-step of the tile

    auto aoff = [&](int t) {
        return (((kc * 32 + t * 2 + qm) * 4 + mt) * 64 + lane) << 3;
    };
    auto mfma4 = [&](const _Float16* wf, half8 a) {
#pragma unroll
        for (int j = 0; j < 4; ++j) {
            half8 b = *(const half8*)&wf[(((j * 2 + qm) * 64 + lane) + j) * 8];
            acc[j] = __builtin_amdgcn_mfma_f32_16x16x32_f16(a, b, acc[j], 0, 0, 0);
        }
    };

    if (kc == 0) {
        // ================= 6-bit region =================
        auto deq6 = [](int b0, int b1, int b2, int b3, int b4, int b5, float s) -> half8 {
            int v0 = b0 & 63;
            int v1 = ((b0 >> 6) & 3) | ((b1 & 15) << 2);
            int v2 = ((b1 >> 4) & 15) | ((b2 & 3) << 4);
            int v3 = (b2 >> 2) & 63;
            int v4 = b3 & 63;
            int v5 = ((b3 >> 6) & 3) | ((b4 & 15) << 2);
            int v6 = ((b4 >> 4) & 15) | ((b5 & 3) << 4);
            int v7 = (b5 >> 2) & 63;
            half8 w;
            w[0] = (_Float16)(((float)v0 - 31.0f) * s);
            w[1] = (_Float16)(((float)v1 - 31.0f) * s);
            w[2] = (_Float16)(((float)v2 - 31.0f) * s);
            w[3] = (_Float16)(((float)v3 - 31.0f) * s);
            w[4] = (_Float16)(((float)v4 - 31.0f) * s);
            w[5] = (_Float16)(((float)v5 - 31.0f) * s);
            w[6] = (_Float16)(((float)v6 - 31.0f) * s);
            w[7] = (_Float16)(((float)v7 - 31.0f) * s);
            return w;
        };
        const int*   base  = Wh + n0 + col;
        const float* sbase = sh + n0 + col;
        int A0, A1, A2, A3, A4, A5; float As;           // even-tile slot
        int B0, B1, B2, B3, B4, B5; float Bs;           // odd-tile slot
        half8 xaE, xaO;
        {   // prologue: tiles 0 and 1
            const int* bp = base + 3 * (kg * 2) * NFEAT;
            A0 = bp[0];         A1 = bp[NFEAT];     A2 = bp[2 * NFEAT];
            A3 = bp[3 * NFEAT]; A4 = bp[4 * NFEAT]; A5 = bp[5 * NFEAT];
            As = sbase[0];
            bp = base + 3 * (16 + kg * 2) * NFEAT;
            B0 = bp[0];         B1 = bp[NFEAT];     B2 = bp[2 * NFEAT];
            B3 = bp[3 * NFEAT]; B4 = bp[4 * NFEAT]; B5 = bp[5 * NFEAT];
            Bs = sbase[0];
            xaE = *(const half8*)(xfrag + aoff(0));
            xaO = *(const half8*)(xfrag + aoff(1));
        }
        for (int i = 0; i < 8; ++i) {
            {   // ---- even phase: tile 2i ----
                half8 w = deq6(A0, A1, A2, A3, A4, A5, As);
                half8 acur = xaE;
                *(half8*)&Wfrag[0][woff] = w;
                const int tp = (i < 7) ? 2 * i + 2 : 14;    // prefetch depth 2
                const int* bp = base + 3 * (tp * 16 + kg * 2) * NFEAT;
                A0 = bp[0];         A1 = bp[NFEAT];     A2 = bp[2 * NFEAT];
                A3 = bp[3 * NFEAT]; A4 = bp[4 * NFEAT]; A5 = bp[5 * NFEAT];
                As = sbase[(tp >> 1) * NFEAT];
                xaE = *(const half8*)(xfrag + aoff(tp));
                BARRIER_KEEP_INFLIGHT();
                mfma4(Wfrag[0], acur);
            }
            {   // ---- odd phase: tile 2i+1 ----
                half8 w = deq6(B0, B1, B2, B3, B4, B5, Bs);
                half8 acur = xaO;
                *(half8*)&Wfrag[1][woff] = w;
                const int tp = (i < 7) ? 2 * i + 3 : 15;
                const int* bp = base + 3 * (tp * 16 + kg * 2) * NFEAT;
                B0 = bp[0];         B1 = bp[NFEAT];     B2 = bp[2 * NFEAT];
                B3 = bp[3 * NFEAT]; B4 = bp[4 * NFEAT]; B5 = bp[5 * NFEAT];
                Bs = sbase[(tp >> 1) * NFEAT];
                xaO = *(const half8*)(xfrag + aoff(tp));
                BARRIER_KEEP_INFLIGHT();
                mfma4(Wfrag[1], acur);
            }
        }
    } else {
        // ================= 5-bit region =================
        auto deq5 = [](int b0, int b1, int b2, int b3, int b4, float s) -> half8 {
            int v0 = b0 & 31;
            int v1 = ((b0 >> 5) & 7) | ((b1 & 3) << 3);
            int v2 = (b1 >> 2) & 31;
            int v3 = ((b1 >> 7) & 1) | ((b2 & 15) << 1);
            int v4 = ((b2 >> 4) & 15) | ((b3 & 1) << 4);
            int v5 = (b3 >> 1) & 31;
            int v6 = ((b3 >> 6) & 3) | ((b4 & 7) << 2);
            int v7 = (b4 >> 3) & 31;
            half8 w;
            w[0] = (_Float16)(((float)v0 - 15.0f) * s);
            w[1] = (_Float16)(((float)v1 - 15.0f) * s);
            w[2] = (_Float16)(((float)v2 - 15.0f) * s);
            w[3] = (_Float16)(((float)v3 - 15.0f) * s);
            w[4] = (_Float16)(((float)v4 - 15.0f) * s);
            w[5] = (_Float16)(((float)v5 - 15.0f) * s);
            w[6] = (_Float16)(((float)v6 - 15.0f) * s);
            w[7] = (_Float16)(((float)v7 - 15.0f) * s);
            return w;
        };
        const int*   base  = Wl + n0 + col;
        const float* sbase = sl + n0 + col;
        const int Gbase     = (kc - 1) * 128;           // G = Gbase + t*8 + kg
        const int sbase_row = (kc - 1) * 8;             // scale row = sbase_row + (t>>1)
        int A0, A1, A2, A3, A4; float As;
        int B0, B1, B2, B3, B4; float Bs;
        half8 xaE, xaO;
        {   // prologue: tiles 0 and 1
            const int* bp = base + 5 * (Gbase + kg) * NFEAT;
            A0 = bp[0]; A1 = bp[NFEAT]; A2 = bp[2 * NFEAT];
            A3 = bp[3 * NFEAT]; A4 = bp[4 * NFEAT];
            As = sbase[sbase_row * NFEAT];
            bp = base + 5 * (Gbase + 8 + kg) * NFEAT;
            B0 = bp[0]; B1 = bp[NFEAT]; B2 = bp[2 * NFEAT];
            B3 = bp[3 * NFEAT]; B4 = bp[4 * NFEAT];
            Bs = sbase[sbase_row * NFEAT];
            xaE = *(const half8*)(xfrag + aoff(0));
            xaO = *(const half8*)(xfrag + aoff(1));
        }
        for (int i = 0; i < 8; ++i) {
            {   // ---- even phase: tile 2i ----
                half8 w = deq5(A0, A1, A2, A3, A4, As);
                half8 acur = xaE;
                *(half8*)&Wfrag[0][woff] = w;
                const int tp = (i < 7) ? 2 * i + 2 : 14;
                const int* bp = base + 5 * (Gbase + tp * 8 + kg) * NFEAT;
                A0 = bp[0]; A1 = bp[NFEAT]; A2 = bp[2 * NFEAT];
                A3 = bp[3 * NFEAT]; A4 = bp[4 * NFEAT];
                As = sbase[(sbase_row + (tp >> 1)) * NFEAT];
                xaE = *(const half8*)(xfrag + aoff(tp));
                BARRIER_KEEP_INFLIGHT();
                mfma4(Wfrag[0], acur);
            }
            {   // ---- odd phase: tile 2i+1 ----
                half8 w = deq5(B0, B1, B2, B3, B4, Bs);
                half8 acur = xaO;
                *(half8*)&Wfrag[1][woff] = w;
                const int tp = (i < 7) ? 2 * i + 3 : 15;
                const int* bp = base + 5 * (Gbase + tp * 8 + kg) * NFEAT;
                B0 = bp[0]; B1 = bp[NFEAT]; B2 = bp[2 * NFEAT];
                B3 = bp[3 * NFEAT]; B4 = bp[4 * NFEAT];
                Bs = sbase[(sbase_row + (tp >> 1)) * NFEAT];
                xaO = *(const half8*)(xfrag + aoff(tp));
                BARRIER_KEEP_INFLIGHT();
                mfma4(Wfrag[1], acur);
            }
        }
    }

    // ---- epilogue: fold q=1 waves into q=0 waves via LDS, then store ----
    __syncthreads();                                    // full drain (also retires dead prefetches)
    float* red = (float*)&Wfrag[0][0];                  // 16*256 floats = 16 KB
    if (wave >= 4) {
#pragma unroll
        for (int j = 0; j < 4; ++j)
#pragma unroll
            for (int r = 0; r < 4; ++r)
                red[(j * 4 + r) * 256 + (wave - 4) * 64 + lane] = acc[j][r];
    }
    __syncthreads();
    if (wave < 4) {
#pragma unroll
        for (int j = 0; j < 4; ++j)
#pragma unroll
            for (int r = 0; r < 4; ++r)
                acc[j][r] += red[(j * 4 + r) * 256 + wave * 64 + lane];

        // D row = wave*16 + (lane>>4)*4 + r, col = lane&15
        const int rb = wave * 16 + ((lane >> 4) << 2);
        const int cb = lane & 15;
        if (atomic_mode) {
#pragma unroll
            for (int j = 0; j < 4; ++j)
#pragma unroll
                for (int r = 0; r < 4; ++r)
                    atomicAdd(&dst[(rb + r) * NFEAT + n0 + j * 16 + cb], acc[j][r]);
        } else {
            float* base = dst + (size_t)kc * 64 * NFEAT;
#pragma unroll
            for (int j = 0; j < 4; ++j)
#pragma unroll
                for (int r = 0; r < 4; ++r)
                    base[(rb + r) * NFEAT + n0 + j * 16 + cb] = acc[j][r];
        }
    }
}

// ---------------- reduce: out = bias + sum_kc partial[kc] ----------------
__global__ __launch_bounds__(256) void reduce_out(const float* __restrict__ part,
                                                  const float* __restrict__ bias,
                                                  float* __restrict__ out) {
    const int idx = blockIdx.x * 256 + threadIdx.x;    // 0..176127 (float4 units)
    const int f   = idx * 4;
    const int n   = f % NFEAT;                          // NFEAT % 4 == 0 -> same row
    f32x4 a = *(const f32x4*)(part + f);
    f32x4 b = *(const f32x4*)(part + 704512 + f);
    f32x4 c = *(const f32x4*)(part + 2 * 704512 + f);
    f32x4 d = *(const f32x4*)(part + 3 * 704512 + f);
    f32x4 bi = *(const f32x4*)(bias + n);
    *(f32x4*)(out + f) = a + b + c + d + bi;
}

__global__ __launch_bounds__(256) void init_bias(const float* __restrict__ bias,
                                                 float* __restrict__ out) {
    const int idx = blockIdx.x * 256 + threadIdx.x;    // 0..704511
    out[idx] = bias[idx % NFEAT];
}

extern "C" void kernel_launch(void* const* d_in, const int* in_sizes, int n_in,
                              void* d_out, int out_size, void* d_ws, size_t ws_size,
                              hipStream_t stream) {
    const float* x    = (const float*)d_in[0];
    const int*   Wh   = (const int*)d_in[1];
    const int*   Wl   = (const int*)d_in[2];
    const float* sh   = (const float*)d_in[3];
    const float* sl   = (const float*)d_in[4];
    const int*   col  = (const int*)d_in[5];
    const float* bias = (const float*)d_in[6];
    float* out = (float*)d_out;

    _Float16* xfrag = (_Float16*)d_ws;                 // 512 KB
    const size_t xfrag_bytes = 64 * KTOT * sizeof(_Float16);
    const size_t part_bytes  = 4ull * 64 * NFEAT * sizeof(float);   // 11.27 MB

    prep_xfrag<<<1024, 256, 0, stream>>>(x, col, xfrag);

    dim3 grid(172, 4);
    if (ws_size >= xfrag_bytes + part_bytes) {
        float* part = (float*)((char*)d_ws + xfrag_bytes);
        gemm_kernel<<<grid, 512, 0, stream>>>(Wh, Wl, sh, sl, xfrag, part, 0);
        reduce_out<<<688, 256, 0, stream>>>(part, bias, out);
    } else {
        init_bias<<<2752, 256, 0, stream>>>(bias, out);
        gemm_kernel<<<grid, 512, 0, stream>>>(Wh, Wl, sh, sl, xfrag, out, 1);
    }
}